// Round 2
// baseline (224.417 us; speedup 1.0000x reference)
//
#include <hip/hip_runtime.h>
#include <math.h>

#define N_LEVELS 24
#define CAPACITY 262144u
#define CAP_MASK 0x3FFFFu
#define PTS 512            // points per block tile
#define LPG 8              // levels per group (one 64B out line = 8 levels)

struct ScaleArg { float s[N_LEVELS]; };

struct Prep {
    float w0, w1, w2, w3;
    unsigned i0, i1, i2, i3;
};

// Weights + hash indices for one (point, level). Bit-exact vs numpy f32 ref:
// no FMA contraction, IEEE divide, rintf == np.round (half-even).
__device__ __forceinline__ Prep permuto_prep(
    float p0, float p1, float p2,
    float scale, float s0, float s1, float s2)
{
#pragma clang fp contract(off)
    // f32(INV_STD_DEV / sqrt((i+1)*(i+2))), INV_STD_DEV = 4*sqrt(2/3)
    const float sf0 = 2.3094010767585034f;
    const float sf1 = 1.3333333333333335f;
    const float sf2 = 0.9428090415820634f;

    const float q0 = p0 / scale + s0;
    const float q1 = p1 / scale + s1;
    const float q2 = p2 / scale + s2;
    const float cf0 = q0 * sf0;
    const float cf1 = q1 * sf1;
    const float cf2 = q2 * sf2;

    const float rc1 = cf2 + cf1;
    const float el0 = rc1 + cf0;
    const float el1 = rc1 - cf0;
    const float el2 = cf2 - 2.0f * cf1;
    const float el3 = 0.0f - 3.0f * cf2;

    float r0 = rintf(el0 * 0.25f) * 4.0f;
    float r1 = rintf(el1 * 0.25f) * 4.0f;
    float r2 = rintf(el2 * 0.25f) * 4.0f;
    float r3 = rintf(el3 * 0.25f) * 4.0f;

    const float d0 = el0 - r0;
    const float d1 = el1 - r1;
    const float d2 = el2 - r2;
    const float d3 = el3 - r3;

    int k0 = 0, k1 = 0, k2 = 0, k3 = 0;
    if (d0 < d1) k0++; else k1++;
    if (d0 < d2) k0++; else k2++;
    if (d0 < d3) k0++; else k3++;
    if (d1 < d2) k1++; else k2++;
    if (d1 < d3) k1++; else k3++;
    if (d2 < d3) k2++; else k3++;

    const int s = (int)rintf((((r0 + r1) + r2) + r3) * 0.25f);
    k0 += s; k1 += s; k2 += s; k3 += s;

    if (k0 < 0) { k0 += 4; r0 += 4.0f; } else if (k0 > 3) { k0 -= 4; r0 -= 4.0f; }
    if (k1 < 0) { k1 += 4; r1 += 4.0f; } else if (k1 > 3) { k1 -= 4; r1 -= 4.0f; }
    if (k2 < 0) { k2 += 4; r2 += 4.0f; } else if (k2 > 3) { k2 -= 4; r2 -= 4.0f; }
    if (k3 < 0) { k3 += 4; r3 += 4.0f; } else if (k3 > 3) { k3 -= 4; r3 -= 4.0f; }

    const float dl0 = (el0 - r0) * 0.25f;
    const float dl1 = (el1 - r1) * 0.25f;
    const float dl2 = (el2 - r2) * 0.25f;
    const float dl3 = (el3 - r3) * 0.25f;

    const float g0 = (k0 == 0 ? dl0 : 0.0f) + (k1 == 0 ? dl1 : 0.0f) + (k2 == 0 ? dl2 : 0.0f) + (k3 == 0 ? dl3 : 0.0f);
    const float g1 = (k0 == 1 ? dl0 : 0.0f) + (k1 == 1 ? dl1 : 0.0f) + (k2 == 1 ? dl2 : 0.0f) + (k3 == 1 ? dl3 : 0.0f);
    const float g2 = (k0 == 2 ? dl0 : 0.0f) + (k1 == 2 ? dl1 : 0.0f) + (k2 == 2 ? dl2 : 0.0f) + (k3 == 2 ? dl3 : 0.0f);
    const float g3 = (k0 == 3 ? dl0 : 0.0f) + (k1 == 3 ? dl1 : 0.0f) + (k2 == 3 ? dl2 : 0.0f) + (k3 == 3 ? dl3 : 0.0f);

    Prep out;
    out.w0 = g3 + 1.0f - g0;
    out.w1 = g2 - g3;
    out.w2 = g1 - g2;
    out.w3 = g0 - g1;

    const int i0 = (int)r0;
    const int i1 = (int)r1;
    const int i2 = (int)r2;

    unsigned idx[4];
#pragma unroll
    for (int r = 0; r < 4; ++r) {
        const int key0 = i0 + r - ((k0 > 3 - r) ? 4 : 0);
        const int key1 = i1 + r - ((k1 > 3 - r) ? 4 : 0);
        const int key2 = i2 + r - ((k2 > 3 - r) ? 4 : 0);
        const unsigned hsh = (unsigned)key0 * 2654435761u
                           ^ (unsigned)key1 * 805459861u
                           ^ (unsigned)key2 * 3674653429u;
        idx[r] = hsh & CAP_MASK;
    }
    out.i0 = idx[0]; out.i1 = idx[1]; out.i2 = idx[2]; out.i3 = idx[3];
    return out;
}

// R9 fused single-pass: block = one level-group (8 levels) x 512 points.
// Rationale (R8 post-mortem): transpose occupancy fix moved total time 0 us
// -> the ~90us gap is attached to the 48MB ws round-trip itself (dirty-L2
// flush at kernel boundary + pass-2 read-back), not its access pattern.
// One out cache line (64B) = levels 8g..8g+7 of one point, so a level-group
// block can assemble full lines in LDS and write out directly: no ws at all.
// HBM traffic 192MB -> ~105MB (pos 9 + tables ~48 + out 50).
// Locality: group 1 (lvl 8-15) pinned to XCDs 0-3, group 2 (16-23) to XCDs
// 4-7, group 0 (cheap, 1.5MB total) sliced over all. Grid 1536, ~1280
// resident -> blocks of a group start together and convoy through l=0..7,
// instantaneous per-XCD working set ~= current level (2MB) + cheap (1.5MB)
// fitting 4MB L2. 8 gathers in flight per thread (2 points x 4 corners).
__global__ __launch_bounds__(256)
void permuto_fused(const float* __restrict__ pos,
                   const float* __restrict__ lattice,
                   const float* __restrict__ rshift,
                   const float* __restrict__ anneal,
                   float4* __restrict__ out,
                   ScaleArg sc, int npts, int balanced, int chunks)
{
#pragma clang fp contract(off)
    int group, chunk;
    if (balanced) {
        // npts == 262144: 512 chunks/group, 1536 blocks, xcd = blockIdx&7
        const int xcd  = blockIdx.x & 7;
        const int slot = blockIdx.x >> 3;              // 0..191
        if (slot < 128) {                              // heavy groups
            group = 1 + (xcd >> 2);                    // xcd 0-3 -> g1, 4-7 -> g2
            chunk = (slot << 2) | (xcd & 3);           // covers 0..511
        } else {                                       // cheap group 0
            group = 0;
            chunk = ((slot - 128) << 3) | xcd;         // covers 0..511
        }
    } else {
        group = blockIdx.x / chunks;
        chunk = blockIdx.x - group * chunks;
    }

    const int t = threadIdx.x;
    const int pbase = chunk * PTS;

    __shared__ float2 sh[LPG][PTS];                    // 32 KB -> 5 blocks/CU

    // two points per thread, coords held in regs across the level loop
    const int n0 = pbase + t;
    const int n1 = pbase + t + 256;
    float p0x = 0.f, p0y = 0.f, p0z = 0.f;
    float p1x = 0.f, p1y = 0.f, p1z = 0.f;
    if (n0 < npts) { p0x = pos[n0 * 3 + 0]; p0y = pos[n0 * 3 + 1]; p0z = pos[n0 * 3 + 2]; }
    if (n1 < npts) { p1x = pos[n1 * 3 + 0]; p1y = pos[n1 * 3 + 1]; p1z = pos[n1 * 3 + 2]; }

#pragma unroll
    for (int l = 0; l < LPG; ++l) {
        const int level = group * LPG + l;
        const float scale = sc.s[level];
        const float s0 = rshift[level * 3 + 0];        // wave-uniform -> scalar
        const float s1 = rshift[level * 3 + 1];
        const float s2 = rshift[level * 3 + 2];
        const float a  = anneal[level];
        const float2* __restrict__ tab =
            (const float2*)lattice + (size_t)level * CAPACITY;

        const Prep A = permuto_prep(p0x, p0y, p0z, scale, s0, s1, s2);
        const Prep B = permuto_prep(p1x, p1y, p1z, scale, s0, s1, s2);

        // 8 gathers all in flight before first use (hash-masked: always in-bounds)
        const float2 va0 = tab[A.i0];
        const float2 va1 = tab[A.i1];
        const float2 va2 = tab[A.i2];
        const float2 va3 = tab[A.i3];
        const float2 vb0 = tab[B.i0];
        const float2 vb1 = tab[B.i1];
        const float2 vb2 = tab[B.i2];
        const float2 vb3 = tab[B.i3];

        const float ax = A.w0 * va0.x + A.w1 * va1.x + A.w2 * va2.x + A.w3 * va3.x;
        const float ay = A.w0 * va0.y + A.w1 * va1.y + A.w2 * va2.y + A.w3 * va3.y;
        const float bx = B.w0 * vb0.x + B.w1 * vb1.x + B.w2 * vb2.x + B.w3 * vb3.x;
        const float by = B.w0 * vb0.y + B.w1 * vb1.y + B.w2 * vb2.y + B.w3 * vb3.y;

        sh[l][t]       = make_float2(ax * a, ay * a);
        sh[l][t + 256] = make_float2(bx * a, by * a);
    }
    __syncthreads();

    // write phase: 512 pts x 4 float4 = 2048 float4, 8 per thread.
    // 4-lane clusters (same p, j=0..3) write one aligned full 64B line;
    // cluster stride 192B. Exactly 50MB HBM write, no partial lines.
#pragma unroll
    for (int k = 0; k < 8; ++k) {
        const int q = k * 256 + t;                     // 0..2047
        const int p = q >> 2;                          // local point
        const int j = q & 3;                           // float4 within group-line
        const int n = pbase + p;
        if (n < npts) {
            const float2 va = sh[2 * j][p];            // group-levels 2j, 2j+1
            const float2 vb = sh[2 * j + 1][p];
            out[(size_t)n * 12 + group * 4 + j] = make_float4(va.x, va.y, vb.x, vb.y);
        }
    }
}

extern "C" void kernel_launch(void* const* d_in, const int* in_sizes, int n_in,
                              void* d_out, int out_size, void* d_ws, size_t ws_size,
                              hipStream_t stream) {
    const float* pos     = (const float*)d_in[0];
    const float* lattice = (const float*)d_in[1];
    const float* rshift  = (const float*)d_in[2];
    const float* anneal  = (const float*)d_in[3];
    const int npts = in_sizes[0] / 3;

    // np.geomspace(1.0, 1e-4, 24).astype(f32): 10**(i * (-4/23)), endpoints pinned
    ScaleArg sc;
    for (int i = 0; i < N_LEVELS; ++i)
        sc.s[i] = (float)pow(10.0, (double)i * (-4.0 / 23.0));
    sc.s[0] = 1.0f;
    sc.s[N_LEVELS - 1] = 1e-4f;

    const int C = (npts + PTS - 1) / PTS;              // chunks per group
    const int balanced = (C == 512) ? 1 : 0;           // npts == 262144 path
    permuto_fused<<<3 * C, 256, 0, stream>>>(
        pos, lattice, rshift, anneal, (float4*)d_out, sc, npts, balanced, C);
}

// Round 3
// 201.562 us; speedup vs baseline: 1.1134x; 1.1134x over previous
//
#include <hip/hip_runtime.h>
#include <math.h>

#define N_LEVELS 24
#define CAPACITY 262144u
#define CAP_MASK 0x3FFFFu
#define PTS 512            // points per gather block (2 per thread)

struct ScaleArg { float s[N_LEVELS]; };

struct Prep {
    float w0, w1, w2, w3;
    unsigned i0, i1, i2, i3;
};

// Weights + hash indices for one (point, level). Bit-exact vs numpy f32 ref:
// no FMA contraction, IEEE divide, rintf == np.round (half-even).
__device__ __forceinline__ Prep permuto_prep(
    float p0, float p1, float p2,
    float scale, float s0, float s1, float s2)
{
#pragma clang fp contract(off)
    // f32(INV_STD_DEV / sqrt((i+1)*(i+2))), INV_STD_DEV = 4*sqrt(2/3)
    const float sf0 = 2.3094010767585034f;
    const float sf1 = 1.3333333333333335f;
    const float sf2 = 0.9428090415820634f;

    const float q0 = p0 / scale + s0;
    const float q1 = p1 / scale + s1;
    const float q2 = p2 / scale + s2;
    const float cf0 = q0 * sf0;
    const float cf1 = q1 * sf1;
    const float cf2 = q2 * sf2;

    const float rc1 = cf2 + cf1;
    const float el0 = rc1 + cf0;
    const float el1 = rc1 - cf0;
    const float el2 = cf2 - 2.0f * cf1;
    const float el3 = 0.0f - 3.0f * cf2;

    float r0 = rintf(el0 * 0.25f) * 4.0f;
    float r1 = rintf(el1 * 0.25f) * 4.0f;
    float r2 = rintf(el2 * 0.25f) * 4.0f;
    float r3 = rintf(el3 * 0.25f) * 4.0f;

    const float d0 = el0 - r0;
    const float d1 = el1 - r1;
    const float d2 = el2 - r2;
    const float d3 = el3 - r3;

    int k0 = 0, k1 = 0, k2 = 0, k3 = 0;
    if (d0 < d1) k0++; else k1++;
    if (d0 < d2) k0++; else k2++;
    if (d0 < d3) k0++; else k3++;
    if (d1 < d2) k1++; else k2++;
    if (d1 < d3) k1++; else k3++;
    if (d2 < d3) k2++; else k3++;

    const int s = (int)rintf((((r0 + r1) + r2) + r3) * 0.25f);
    k0 += s; k1 += s; k2 += s; k3 += s;

    if (k0 < 0) { k0 += 4; r0 += 4.0f; } else if (k0 > 3) { k0 -= 4; r0 -= 4.0f; }
    if (k1 < 0) { k1 += 4; r1 += 4.0f; } else if (k1 > 3) { k1 -= 4; r1 -= 4.0f; }
    if (k2 < 0) { k2 += 4; r2 += 4.0f; } else if (k2 > 3) { k2 -= 4; r2 -= 4.0f; }
    if (k3 < 0) { k3 += 4; r3 += 4.0f; } else if (k3 > 3) { k3 -= 4; r3 -= 4.0f; }

    const float dl0 = (el0 - r0) * 0.25f;
    const float dl1 = (el1 - r1) * 0.25f;
    const float dl2 = (el2 - r2) * 0.25f;
    const float dl3 = (el3 - r3) * 0.25f;

    const float g0 = (k0 == 0 ? dl0 : 0.0f) + (k1 == 0 ? dl1 : 0.0f) + (k2 == 0 ? dl2 : 0.0f) + (k3 == 0 ? dl3 : 0.0f);
    const float g1 = (k0 == 1 ? dl0 : 0.0f) + (k1 == 1 ? dl1 : 0.0f) + (k2 == 1 ? dl2 : 0.0f) + (k3 == 1 ? dl3 : 0.0f);
    const float g2 = (k0 == 2 ? dl0 : 0.0f) + (k1 == 2 ? dl1 : 0.0f) + (k2 == 2 ? dl2 : 0.0f) + (k3 == 2 ? dl3 : 0.0f);
    const float g3 = (k0 == 3 ? dl0 : 0.0f) + (k1 == 3 ? dl1 : 0.0f) + (k2 == 3 ? dl2 : 0.0f) + (k3 == 3 ? dl3 : 0.0f);

    Prep out;
    out.w0 = g3 + 1.0f - g0;
    out.w1 = g2 - g3;
    out.w2 = g1 - g2;
    out.w3 = g0 - g1;

    const int i0 = (int)r0;
    const int i1 = (int)r1;
    const int i2 = (int)r2;

    unsigned idx[4];
#pragma unroll
    for (int r = 0; r < 4; ++r) {
        const int key0 = i0 + r - ((k0 > 3 - r) ? 4 : 0);
        const int key1 = i1 + r - ((k1 > 3 - r) ? 4 : 0);
        const int key2 = i2 + r - ((k2 > 3 - r) ? 4 : 0);
        const unsigned hsh = (unsigned)key0 * 2654435761u
                           ^ (unsigned)key1 * 805459861u
                           ^ (unsigned)key2 * 3674653429u;
        idx[r] = hsh & CAP_MASK;
    }
    out.i0 = idx[0]; out.i1 = idx[1]; out.i2 = idx[2]; out.i3 = idx[3];
    return out;
}

// Pass 1: level-major gather with XCD affinity (xcd = blockIdx&7).
// R9 post-mortem: per-block level loops thrash L2 (fused: FETCH 46->370MB);
// one level per block is the only schedule keeping tables fetched-once.
// Fixed graph overhead ~82us; transpose ~7us (ws LLC-resident) -> the gather
// IS the remaining cost. R10: 2 points/thread = 8 gathers in flight (R2's
// fused proved ~44 VGPR, still 32 waves/CU) to push L2 request rate from
// ~12 toward ~16 req/cyc/XCD. Schedule (npts==262144, 512-pt chunks,
// 512 chunks/level, 12288 blocks):
//   phase A (slot 0..511):    level 8+xcd,  whole table, L2-resident
//   phase B (slot 512..1023): level 16+xcd, whole table, L2-resident
//   phase C (slot 1024..1535): levels 0..7 sliced over all XCDs
// Plain loads only: NT kills L2/L3 residency (R6: FETCH 54->354MB).
__global__ __launch_bounds__(256)
void permuto_gather(const float* __restrict__ pos,
                    const float* __restrict__ lattice,
                    const float* __restrict__ rshift,
                    const float* __restrict__ anneal,
                    float2* __restrict__ ws,
                    ScaleArg sc, int npts, int balanced, int chunksPerLevel)
{
#pragma clang fp contract(off)
    int level, chunk;
    const int xcd = blockIdx.x & 7;
    if (balanced) {
        const int slot = blockIdx.x >> 3;
        if (slot < 512)       { level = 8 + xcd;  chunk = slot; }
        else if (slot < 1024) { level = 16 + xcd; chunk = slot - 512; }
        else {
            const int s = slot - 1024;          // 0..511
            level = s & 7;                      // cheap levels 0..7
            chunk = (s & ~7) | xcd;             // covers all 512 chunks/level
        }
    } else {
        const int j = blockIdx.x >> 3;
        const int phase = j / chunksPerLevel;
        chunk = j - phase * chunksPerLevel;
        level = phase * 8 + xcd;
    }

    const int t = threadIdx.x;
    const int n0 = chunk * PTS + t;
    const int n1 = n0 + 256;

    const float scale = sc.s[level];
    const float s0 = rshift[level * 3 + 0];      // wave-uniform -> scalar loads
    const float s1 = rshift[level * 3 + 1];
    const float s2 = rshift[level * 3 + 2];
    const float a  = anneal[level];

    float p0x = 0.f, p0y = 0.f, p0z = 0.f;
    float p1x = 0.f, p1y = 0.f, p1z = 0.f;
    if (n0 < npts) { p0x = pos[n0 * 3 + 0]; p0y = pos[n0 * 3 + 1]; p0z = pos[n0 * 3 + 2]; }
    if (n1 < npts) { p1x = pos[n1 * 3 + 0]; p1y = pos[n1 * 3 + 1]; p1z = pos[n1 * 3 + 2]; }

    const float2* __restrict__ tab = (const float2*)lattice + (size_t)level * CAPACITY;

    const Prep A = permuto_prep(p0x, p0y, p0z, scale, s0, s1, s2);
    const Prep B = permuto_prep(p1x, p1y, p1z, scale, s0, s1, s2);

    // 8 gathers all in flight before first use (hash-masked: always in-bounds)
    const float2 va0 = tab[A.i0];
    const float2 va1 = tab[A.i1];
    const float2 va2 = tab[A.i2];
    const float2 va3 = tab[A.i3];
    const float2 vb0 = tab[B.i0];
    const float2 vb1 = tab[B.i1];
    const float2 vb2 = tab[B.i2];
    const float2 vb3 = tab[B.i3];

    const float ax = A.w0 * va0.x + A.w1 * va1.x + A.w2 * va2.x + A.w3 * va3.x;
    const float ay = A.w0 * va0.y + A.w1 * va1.y + A.w2 * va2.y + A.w3 * va3.y;
    const float bx = B.w0 * vb0.x + B.w1 * vb1.x + B.w2 * vb2.x + B.w3 * vb3.x;
    const float by = B.w0 * vb0.y + B.w1 * vb1.y + B.w2 * vb2.y + B.w3 * vb3.y;

    if (n0 < npts) ws[(size_t)level * npts + n0] = make_float2(ax * a, ay * a);
    if (n1 < npts) ws[(size_t)level * npts + n1] = make_float2(bx * a, by * a);
}

// Pass 2: (L,N,2) -> (N,L,2) via LDS tile; ~7us (ws LLC-resident).
// 64-point tile: LDS 12.5KB/block, 8 blocks/CU, grid 4096.
__global__ __launch_bounds__(256)
void permuto_transpose(const float2* __restrict__ ws,
                       float4* __restrict__ out, int npts)
{
    __shared__ float2 sh[N_LEVELS][65];
    const int t = threadIdx.x;
    const int pbase = blockIdx.x * 64;
    const int valid = npts - pbase;

    if (valid >= 64) {
        // load 24 levels x 64 points: 1536 float2, 6 per thread
        float2 r[6];
#pragma unroll
        for (int k = 0; k < 6; ++k) {
            const int idx = k * 256 + t;
            const int l = idx >> 6;
            const int p = idx & 63;
            r[k] = ws[(size_t)l * npts + pbase + p];
        }
#pragma unroll
        for (int k = 0; k < 6; ++k) {
            const int idx = k * 256 + t;
            sh[idx >> 6][idx & 63] = r[k];
        }
        __syncthreads();

        float4* o = out + (size_t)pbase * 12;
#pragma unroll
        for (int s = 0; s < 3; ++s) {
            const int q = s * 256 + t;     // float4 index within block tile (0..767)
            const int p = q / 12;          // local point
            const int j = q - p * 12;      // float4-within-point = levels 2j,2j+1
            const float2 va = sh[2 * j][p];
            const float2 vb = sh[2 * j + 1][p];
            o[q] = make_float4(va.x, va.y, vb.x, vb.y);    // dense 16B/lane
        }
    } else {
        if (t < valid) {
            const int n = pbase + t;
            float4* o = out + (size_t)n * 12;
#pragma unroll
            for (int j = 0; j < 12; ++j) {
                const float2 va = ws[(size_t)(2 * j) * npts + n];
                const float2 vb = ws[(size_t)(2 * j + 1) * npts + n];
                o[j] = make_float4(va.x, va.y, vb.x, vb.y);
            }
        }
    }
}

// Fallback (ws too small): monolithic, one thread per point.
__global__ __launch_bounds__(256)
void permuto_mono(const float* __restrict__ pos,
                  const float* __restrict__ lattice,
                  const float* __restrict__ rshift,
                  const float* __restrict__ anneal,
                  float* __restrict__ out,
                  ScaleArg sc, int npts)
{
#pragma clang fp contract(off)
    __shared__ float sh_shift[N_LEVELS][3];
    __shared__ float sh_ann[N_LEVELS];
    const int tid = threadIdx.x;
    if (tid < N_LEVELS) {
        sh_shift[tid][0] = rshift[tid * 3 + 0];
        sh_shift[tid][1] = rshift[tid * 3 + 1];
        sh_shift[tid][2] = rshift[tid * 3 + 2];
        sh_ann[tid] = anneal[tid];
    }
    __syncthreads();

    const int n = blockIdx.x * 256 + tid;
    if (n >= npts) return;
    const float p0 = pos[n * 3 + 0];
    const float p1 = pos[n * 3 + 1];
    const float p2 = pos[n * 3 + 2];
    float2* outv = (float2*)out + (size_t)n * N_LEVELS;
    for (int l = 0; l < N_LEVELS; ++l) {
        const float2* tab = (const float2*)lattice + (size_t)l * CAPACITY;
        Prep pr = permuto_prep(p0, p1, p2, sc.s[l],
                               sh_shift[l][0], sh_shift[l][1], sh_shift[l][2]);
        float2 v0 = tab[pr.i0], v1 = tab[pr.i1], v2 = tab[pr.i2], v3 = tab[pr.i3];
        float ax = pr.w0 * v0.x + pr.w1 * v1.x + pr.w2 * v2.x + pr.w3 * v3.x;
        float ay = pr.w0 * v0.y + pr.w1 * v1.y + pr.w2 * v2.y + pr.w3 * v3.y;
        outv[l] = make_float2(ax * sh_ann[l], ay * sh_ann[l]);
    }
}

extern "C" void kernel_launch(void* const* d_in, const int* in_sizes, int n_in,
                              void* d_out, int out_size, void* d_ws, size_t ws_size,
                              hipStream_t stream) {
    const float* pos     = (const float*)d_in[0];
    const float* lattice = (const float*)d_in[1];
    const float* rshift  = (const float*)d_in[2];
    const float* anneal  = (const float*)d_in[3];
    const int npts = in_sizes[0] / 3;

    // np.geomspace(1.0, 1e-4, 24).astype(f32): 10**(i * (-4/23)), endpoints pinned
    ScaleArg sc;
    for (int i = 0; i < N_LEVELS; ++i)
        sc.s[i] = (float)pow(10.0, (double)i * (-4.0 / 23.0));
    sc.s[0] = 1.0f;
    sc.s[N_LEVELS - 1] = 1e-4f;

    const size_t ws_need = (size_t)N_LEVELS * (size_t)npts * sizeof(float2);
    if (ws_size >= ws_need) {
        const int C = (npts + PTS - 1) / PTS;      // 512-pt chunks per level
        if (C == 512) {
            // balanced schedule: 8 XCD lanes x 1536 slots (A:8+x, B:16+x, C:0..7 sliced)
            permuto_gather<<<8 * 1536, 256, 0, stream>>>(
                pos, lattice, rshift, anneal, (float2*)d_ws, sc, npts, 1, C);
        } else {
            permuto_gather<<<8 * 3 * C, 256, 0, stream>>>(
                pos, lattice, rshift, anneal, (float2*)d_ws, sc, npts, 0, C);
        }
        const int blocks2 = (npts + 63) / 64;
        permuto_transpose<<<blocks2, 256, 0, stream>>>(
            (const float2*)d_ws, (float4*)d_out, npts);
    } else {
        const int blocks = (npts + 255) / 256;
        permuto_mono<<<blocks, 256, 0, stream>>>(
            pos, lattice, rshift, anneal, (float*)d_out, sc, npts);
    }
}

// Round 4
// 198.965 us; speedup vs baseline: 1.1279x; 1.0131x over previous
//
#include <hip/hip_runtime.h>
#include <math.h>

#define N_LEVELS 24
#define CAPACITY 262144u
#define CAP_MASK 0x3FFFFu
#define PTS 512            // points per gather block (2 per thread)

struct ScaleArg { float s[N_LEVELS]; };

struct Prep {
    float w0, w1, w2, w3;
    unsigned i0, i1, i2, i3;
};

typedef float f32x2 __attribute__((ext_vector_type(2)));

// L1-bypass gather: sc0 => agent scope => skip write-through L1, serve from L2.
// Heavy levels have ~2% L1 hit (0.76-2MB footprint vs 32KB L1); bypassing
// frees the per-CU L1 miss-tracking path, the suspected concurrency limit
// (R3: doubling per-thread MLP was a perfect null => TLP already saturates
// the miss path, not the wave issue).
__device__ __forceinline__ float2 load_tab_sc0(const float2* __restrict__ p) {
    f32x2 v;
    asm volatile("global_load_dwordx2 %0, %1, off sc0"
                 : "=v"(v) : "v"(p));
    return make_float2(v.x, v.y);
}

// Weights + hash indices for one (point, level). Bit-exact vs numpy f32 ref:
// no FMA contraction, IEEE divide, rintf == np.round (half-even).
__device__ __forceinline__ Prep permuto_prep(
    float p0, float p1, float p2,
    float scale, float s0, float s1, float s2)
{
#pragma clang fp contract(off)
    // f32(INV_STD_DEV / sqrt((i+1)*(i+2))), INV_STD_DEV = 4*sqrt(2/3)
    const float sf0 = 2.3094010767585034f;
    const float sf1 = 1.3333333333333335f;
    const float sf2 = 0.9428090415820634f;

    const float q0 = p0 / scale + s0;
    const float q1 = p1 / scale + s1;
    const float q2 = p2 / scale + s2;
    const float cf0 = q0 * sf0;
    const float cf1 = q1 * sf1;
    const float cf2 = q2 * sf2;

    const float rc1 = cf2 + cf1;
    const float el0 = rc1 + cf0;
    const float el1 = rc1 - cf0;
    const float el2 = cf2 - 2.0f * cf1;
    const float el3 = 0.0f - 3.0f * cf2;

    float r0 = rintf(el0 * 0.25f) * 4.0f;
    float r1 = rintf(el1 * 0.25f) * 4.0f;
    float r2 = rintf(el2 * 0.25f) * 4.0f;
    float r3 = rintf(el3 * 0.25f) * 4.0f;

    const float d0 = el0 - r0;
    const float d1 = el1 - r1;
    const float d2 = el2 - r2;
    const float d3 = el3 - r3;

    int k0 = 0, k1 = 0, k2 = 0, k3 = 0;
    if (d0 < d1) k0++; else k1++;
    if (d0 < d2) k0++; else k2++;
    if (d0 < d3) k0++; else k3++;
    if (d1 < d2) k1++; else k2++;
    if (d1 < d3) k1++; else k3++;
    if (d2 < d3) k2++; else k3++;

    const int s = (int)rintf((((r0 + r1) + r2) + r3) * 0.25f);
    k0 += s; k1 += s; k2 += s; k3 += s;

    if (k0 < 0) { k0 += 4; r0 += 4.0f; } else if (k0 > 3) { k0 -= 4; r0 -= 4.0f; }
    if (k1 < 0) { k1 += 4; r1 += 4.0f; } else if (k1 > 3) { k1 -= 4; r1 -= 4.0f; }
    if (k2 < 0) { k2 += 4; r2 += 4.0f; } else if (k2 > 3) { k2 -= 4; r2 -= 4.0f; }
    if (k3 < 0) { k3 += 4; r3 += 4.0f; } else if (k3 > 3) { k3 -= 4; r3 -= 4.0f; }

    const float dl0 = (el0 - r0) * 0.25f;
    const float dl1 = (el1 - r1) * 0.25f;
    const float dl2 = (el2 - r2) * 0.25f;
    const float dl3 = (el3 - r3) * 0.25f;

    const float g0 = (k0 == 0 ? dl0 : 0.0f) + (k1 == 0 ? dl1 : 0.0f) + (k2 == 0 ? dl2 : 0.0f) + (k3 == 0 ? dl3 : 0.0f);
    const float g1 = (k0 == 1 ? dl0 : 0.0f) + (k1 == 1 ? dl1 : 0.0f) + (k2 == 1 ? dl2 : 0.0f) + (k3 == 1 ? dl3 : 0.0f);
    const float g2 = (k0 == 2 ? dl0 : 0.0f) + (k1 == 2 ? dl1 : 0.0f) + (k2 == 2 ? dl2 : 0.0f) + (k3 == 2 ? dl3 : 0.0f);
    const float g3 = (k0 == 3 ? dl0 : 0.0f) + (k1 == 3 ? dl1 : 0.0f) + (k2 == 3 ? dl2 : 0.0f) + (k3 == 3 ? dl3 : 0.0f);

    Prep out;
    out.w0 = g3 + 1.0f - g0;
    out.w1 = g2 - g3;
    out.w2 = g1 - g2;
    out.w3 = g0 - g1;

    const int i0 = (int)r0;
    const int i1 = (int)r1;
    const int i2 = (int)r2;

    unsigned idx[4];
#pragma unroll
    for (int r = 0; r < 4; ++r) {
        const int key0 = i0 + r - ((k0 > 3 - r) ? 4 : 0);
        const int key1 = i1 + r - ((k1 > 3 - r) ? 4 : 0);
        const int key2 = i2 + r - ((k2 > 3 - r) ? 4 : 0);
        const unsigned hsh = (unsigned)key0 * 2654435761u
                           ^ (unsigned)key1 * 805459861u
                           ^ (unsigned)key2 * 3674653429u;
        idx[r] = hsh & CAP_MASK;
    }
    out.i0 = idx[0]; out.i1 = idx[1]; out.i2 = idx[2]; out.i3 = idx[3];
    return out;
}

// Pass 1: level-major gather with XCD affinity (xcd = blockIdx&7).
// R9 post-mortem: per-block level loops thrash L2 (fused: FETCH 46->370MB);
// one level per block is the only schedule keeping tables fetched-once.
// R10 post-mortem: MLP 4->8 was a perfect null => per-CU L1 miss-path
// concurrency (MSHR x ~200cy L2 latency) is the limiter, already TLP-
// saturated. R11: sc0 L1-bypass on heavy-level gathers (L1 hit ~2% there);
// cheap levels 0..7 keep normal loads (real L1 hits). Schedule
// (npts==262144, 512-pt chunks, 512 chunks/level, 12288 blocks):
//   phase A (slot 0..511):     level 8+xcd,  whole table, L2-resident
//   phase B (slot 512..1023):  level 16+xcd, whole table, L2-resident
//   phase C (slot 1024..1535): levels 0..7 sliced over all XCDs
// Plain (non-nt) loads only: NT kills L2/L3 residency (R6: FETCH 54->354MB).
__global__ __launch_bounds__(256)
void permuto_gather(const float* __restrict__ pos,
                    const float* __restrict__ lattice,
                    const float* __restrict__ rshift,
                    const float* __restrict__ anneal,
                    float2* __restrict__ ws,
                    ScaleArg sc, int npts, int balanced, int chunksPerLevel)
{
#pragma clang fp contract(off)
    int level, chunk;
    const int xcd = blockIdx.x & 7;
    if (balanced) {
        const int slot = blockIdx.x >> 3;
        if (slot < 512)       { level = 8 + xcd;  chunk = slot; }
        else if (slot < 1024) { level = 16 + xcd; chunk = slot - 512; }
        else {
            const int s = slot - 1024;          // 0..511
            level = s & 7;                      // cheap levels 0..7
            chunk = (s & ~7) | xcd;             // covers all 512 chunks/level
        }
    } else {
        const int j = blockIdx.x >> 3;
        const int phase = j / chunksPerLevel;
        chunk = j - phase * chunksPerLevel;
        level = phase * 8 + xcd;
    }

    const int t = threadIdx.x;
    const int n0 = chunk * PTS + t;
    const int n1 = n0 + 256;

    const float scale = sc.s[level];
    const float s0 = rshift[level * 3 + 0];      // wave-uniform -> scalar loads
    const float s1 = rshift[level * 3 + 1];
    const float s2 = rshift[level * 3 + 2];
    const float a  = anneal[level];

    float p0x = 0.f, p0y = 0.f, p0z = 0.f;
    float p1x = 0.f, p1y = 0.f, p1z = 0.f;
    if (n0 < npts) { p0x = pos[n0 * 3 + 0]; p0y = pos[n0 * 3 + 1]; p0z = pos[n0 * 3 + 2]; }
    if (n1 < npts) { p1x = pos[n1 * 3 + 0]; p1y = pos[n1 * 3 + 1]; p1z = pos[n1 * 3 + 2]; }

    const float2* __restrict__ tab = (const float2*)lattice + (size_t)level * CAPACITY;

    const Prep A = permuto_prep(p0x, p0y, p0z, scale, s0, s1, s2);
    const Prep B = permuto_prep(p1x, p1y, p1z, scale, s0, s1, s2);

    // 8 gathers all in flight before first use (hash-masked: always in-bounds)
    float2 va0, va1, va2, va3, vb0, vb1, vb2, vb3;
    if (level >= 8) {                            // wave-uniform branch
        va0 = load_tab_sc0(tab + A.i0);
        va1 = load_tab_sc0(tab + A.i1);
        va2 = load_tab_sc0(tab + A.i2);
        va3 = load_tab_sc0(tab + A.i3);
        vb0 = load_tab_sc0(tab + B.i0);
        vb1 = load_tab_sc0(tab + B.i1);
        vb2 = load_tab_sc0(tab + B.i2);
        vb3 = load_tab_sc0(tab + B.i3);
        asm volatile("s_waitcnt vmcnt(0)" ::: "memory");
        __builtin_amdgcn_sched_barrier(0);       // rule #18: pin consumers after wait
    } else {
        va0 = tab[A.i0];
        va1 = tab[A.i1];
        va2 = tab[A.i2];
        va3 = tab[A.i3];
        vb0 = tab[B.i0];
        vb1 = tab[B.i1];
        vb2 = tab[B.i2];
        vb3 = tab[B.i3];
    }

    const float ax = A.w0 * va0.x + A.w1 * va1.x + A.w2 * va2.x + A.w3 * va3.x;
    const float ay = A.w0 * va0.y + A.w1 * va1.y + A.w2 * va2.y + A.w3 * va3.y;
    const float bx = B.w0 * vb0.x + B.w1 * vb1.x + B.w2 * vb2.x + B.w3 * vb3.x;
    const float by = B.w0 * vb0.y + B.w1 * vb1.y + B.w2 * vb2.y + B.w3 * vb3.y;

    if (n0 < npts) ws[(size_t)level * npts + n0] = make_float2(ax * a, ay * a);
    if (n1 < npts) ws[(size_t)level * npts + n1] = make_float2(bx * a, by * a);
}

// Pass 2: (L,N,2) -> (N,L,2) via LDS tile; ~7us (ws LLC-resident).
// 64-point tile: LDS 12.5KB/block, 8 blocks/CU, grid 4096.
__global__ __launch_bounds__(256)
void permuto_transpose(const float2* __restrict__ ws,
                       float4* __restrict__ out, int npts)
{
    __shared__ float2 sh[N_LEVELS][65];
    const int t = threadIdx.x;
    const int pbase = blockIdx.x * 64;
    const int valid = npts - pbase;

    if (valid >= 64) {
        // load 24 levels x 64 points: 1536 float2, 6 per thread
        float2 r[6];
#pragma unroll
        for (int k = 0; k < 6; ++k) {
            const int idx = k * 256 + t;
            const int l = idx >> 6;
            const int p = idx & 63;
            r[k] = ws[(size_t)l * npts + pbase + p];
        }
#pragma unroll
        for (int k = 0; k < 6; ++k) {
            const int idx = k * 256 + t;
            sh[idx >> 6][idx & 63] = r[k];
        }
        __syncthreads();

        float4* o = out + (size_t)pbase * 12;
#pragma unroll
        for (int s = 0; s < 3; ++s) {
            const int q = s * 256 + t;     // float4 index within block tile (0..767)
            const int p = q / 12;          // local point
            const int j = q - p * 12;      // float4-within-point = levels 2j,2j+1
            const float2 va = sh[2 * j][p];
            const float2 vb = sh[2 * j + 1][p];
            o[q] = make_float4(va.x, va.y, vb.x, vb.y);    // dense 16B/lane
        }
    } else {
        if (t < valid) {
            const int n = pbase + t;
            float4* o = out + (size_t)n * 12;
#pragma unroll
            for (int j = 0; j < 12; ++j) {
                const float2 va = ws[(size_t)(2 * j) * npts + n];
                const float2 vb = ws[(size_t)(2 * j + 1) * npts + n];
                o[j] = make_float4(va.x, va.y, vb.x, vb.y);
            }
        }
    }
}

// Fallback (ws too small): monolithic, one thread per point.
__global__ __launch_bounds__(256)
void permuto_mono(const float* __restrict__ pos,
                  const float* __restrict__ lattice,
                  const float* __restrict__ rshift,
                  const float* __restrict__ anneal,
                  float* __restrict__ out,
                  ScaleArg sc, int npts)
{
#pragma clang fp contract(off)
    __shared__ float sh_shift[N_LEVELS][3];
    __shared__ float sh_ann[N_LEVELS];
    const int tid = threadIdx.x;
    if (tid < N_LEVELS) {
        sh_shift[tid][0] = rshift[tid * 3 + 0];
        sh_shift[tid][1] = rshift[tid * 3 + 1];
        sh_shift[tid][2] = rshift[tid * 3 + 2];
        sh_ann[tid] = anneal[tid];
    }
    __syncthreads();

    const int n = blockIdx.x * 256 + tid;
    if (n >= npts) return;
    const float p0 = pos[n * 3 + 0];
    const float p1 = pos[n * 3 + 1];
    const float p2 = pos[n * 3 + 2];
    float2* outv = (float2*)out + (size_t)n * N_LEVELS;
    for (int l = 0; l < N_LEVELS; ++l) {
        const float2* tab = (const float2*)lattice + (size_t)l * CAPACITY;
        Prep pr = permuto_prep(p0, p1, p2, sc.s[l],
                               sh_shift[l][0], sh_shift[l][1], sh_shift[l][2]);
        float2 v0 = tab[pr.i0], v1 = tab[pr.i1], v2 = tab[pr.i2], v3 = tab[pr.i3];
        float ax = pr.w0 * v0.x + pr.w1 * v1.x + pr.w2 * v2.x + pr.w3 * v3.x;
        float ay = pr.w0 * v0.y + pr.w1 * v1.y + pr.w2 * v2.y + pr.w3 * v3.y;
        outv[l] = make_float2(ax * sh_ann[l], ay * sh_ann[l]);
    }
}

extern "C" void kernel_launch(void* const* d_in, const int* in_sizes, int n_in,
                              void* d_out, int out_size, void* d_ws, size_t ws_size,
                              hipStream_t stream) {
    const float* pos     = (const float*)d_in[0];
    const float* lattice = (const float*)d_in[1];
    const float* rshift  = (const float*)d_in[2];
    const float* anneal  = (const float*)d_in[3];
    const int npts = in_sizes[0] / 3;

    // np.geomspace(1.0, 1e-4, 24).astype(f32): 10**(i * (-4/23)), endpoints pinned
    ScaleArg sc;
    for (int i = 0; i < N_LEVELS; ++i)
        sc.s[i] = (float)pow(10.0, (double)i * (-4.0 / 23.0));
    sc.s[0] = 1.0f;
    sc.s[N_LEVELS - 1] = 1e-4f;

    const size_t ws_need = (size_t)N_LEVELS * (size_t)npts * sizeof(float2);
    if (ws_size >= ws_need) {
        const int C = (npts + PTS - 1) / PTS;      // 512-pt chunks per level
        if (C == 512) {
            // balanced schedule: 8 XCD lanes x 1536 slots (A:8+x, B:16+x, C:0..7 sliced)
            permuto_gather<<<8 * 1536, 256, 0, stream>>>(
                pos, lattice, rshift, anneal, (float2*)d_ws, sc, npts, 1, C);
        } else {
            permuto_gather<<<8 * 3 * C, 256, 0, stream>>>(
                pos, lattice, rshift, anneal, (float2*)d_ws, sc, npts, 0, C);
        }
        const int blocks2 = (npts + 63) / 64;
        permuto_transpose<<<blocks2, 256, 0, stream>>>(
            (const float2*)d_ws, (float4*)d_out, npts);
    } else {
        const int blocks = (npts + 255) / 256;
        permuto_mono<<<blocks, 256, 0, stream>>>(
            pos, lattice, rshift, anneal, (float*)d_out, sc, npts);
    }
}